// Round 19
// baseline (474.181 us; speedup 1.0000x reference)
//
#include <hip/hip_runtime.h>

#define BT (256*512)   // 131072 positions
#define HID 128
#define EMB 64
#define CH 32          // scan chunk: steps staged per LDS refill

typedef _Float16 half2_t __attribute__((ext_vector_type(2)));

__device__ inline float fast_tanh(float x) {   // 1 - 2/(exp(2x)+1), ~1e-6 abs err
    float e = __expf(2.f * x);
    return 1.f - __fdividef(2.f, e + 1.f);
}

// pin a float4 in VGPRs (compiler cannot rematerialize past this) — R6 recipe
#define OPQ(v) asm volatile("" : "+v"(v.x), "+v"(v.y), "+v"(v.z), "+v"(v.w))
#define W16PIN \
    OPQ(w0);OPQ(w1);OPQ(w2);OPQ(w3);OPQ(w4);OPQ(w5);OPQ(w6);OPQ(w7); \
    OPQ(w8);OPQ(w9);OPQ(w10);OPQ(w11);OPQ(w12);OPQ(w13);OPQ(w14);OPQ(w15);
// dual-row load: w0..w7 = row r0 K-slice, w8..w15 = row r0+64 same K-slice
#define WDUALLOAD \
    float4 w0=wr0[0],w1=wr0[1],w2=wr0[2],w3=wr0[3],w4=wr0[4],w5=wr0[5],w6=wr0[6],w7=wr0[7], \
           w8=wr1[0],w9=wr1[1],w10=wr1[2],w11=wr1[3],w12=wr1[4],w13=wr1[5],w14=wr1[6],w15=wr1[7];

// fp32 dual-row dot over a 32-value h slice: 8 b128 reads shared by 2 rows
#define DACC(n, m) { float4 hv = hp[n]; \
    a0=fmaf(hv.x,w##n.x,a0); a1=fmaf(hv.y,w##n.y,a1); \
    a2=fmaf(hv.z,w##n.z,a2); a3=fmaf(hv.w,w##n.w,a3); \
    c0=fmaf(hv.x,w##m.x,c0); c1=fmaf(hv.y,w##m.y,c1); \
    c2=fmaf(hv.z,w##m.z,c2); c3=fmaf(hv.w,w##m.w,c3); }
#define DACC8 DACC(0,8) DACC(1,9) DACC(2,10) DACC(3,11) \
              DACC(4,12) DACC(5,13) DACC(6,14) DACC(7,15)

// fp16 dual-row dot over a 32-value h slice: 4 uint4 reads shared by 2 rows
#define BCH(u) __builtin_bit_cast(half2_t, u)
#define FMX2(qq, wa, wb, wc, wd) { \
    half2_t p0=BCH(qq.x), p1=BCH(qq.y), p2=BCH(qq.z), p3=BCH(qq.w); \
    float f0=(float)p0.x, f1=(float)p0.y, f2=(float)p1.x, f3=(float)p1.y, \
          f4=(float)p2.x, f5=(float)p2.y, f6=(float)p3.x, f7=(float)p3.y; \
    a0=fmaf(f0,wa.x,a0); a1=fmaf(f1,wa.y,a1); a2=fmaf(f2,wa.z,a2); a3=fmaf(f3,wa.w,a3); \
    a0=fmaf(f4,wb.x,a0); a1=fmaf(f5,wb.y,a1); a2=fmaf(f6,wb.z,a2); a3=fmaf(f7,wb.w,a3); \
    c0=fmaf(f0,wc.x,c0); c1=fmaf(f1,wc.y,c1); c2=fmaf(f2,wc.z,c2); c3=fmaf(f3,wc.w,c3); \
    c0=fmaf(f4,wd.x,c0); c1=fmaf(f5,wd.y,c1); c2=fmaf(f6,wd.z,c2); c3=fmaf(f7,wd.w,c3); }
#define DOT32H2(hsrc) \
    { uint4 q0h=hsrc[0],q1h=hsrc[1],q2h=hsrc[2],q3h=hsrc[3]; \
      FMX2(q0h,w0,w1,w8,w9) FMX2(q1h,w2,w3,w10,w11) \
      FMX2(q2h,w4,w5,w12,w13) FMX2(q3h,w6,w7,w14,w15) }

// ---------------- kernel 1: embedding gather + layer-1 input GEMM.
// R19 change: waves_per_eu (1,2) -> (1,3). The j-loop's fmac:LDS ratio is
// healthy; the gap vs the ~14 µs VALU floor is exposed latency on the
// x -> stok -> emb-gather HBM chain at only 2 waves/EU. 3 waves/EU keeps
// the ~130 live regs (acc 64 + prefetch 32 + temps) under the 170 budget.
__global__ __launch_bounds__(256)
__attribute__((amdgpu_waves_per_eu(1, 3)))
void k_embed_pre1(
    const int* __restrict__ x, const float* __restrict__ emb,
    const float* __restrict__ Wih1, const float* __restrict__ bih1,
    const float* __restrict__ bhh1, float* __restrict__ pre1)
{
    __shared__ float sA[32][128];
    __shared__ float sW[32][132];
    __shared__ int stok[128];
    const int tid = threadIdx.x;
    const int base = blockIdx.x * 128;
    const int tx = tid & 15, ty = tid >> 4;
    const int ox = tx * 8, py = ty * 8;
    const int pl = tid & 127, half = tid >> 7;
    if (tid < 128) stok[tid] = x[base + tid];
    float acc[8][8];
#pragma unroll
    for (int p = 0; p < 8; ++p)
#pragma unroll
        for (int o = 0; o < 8; ++o) acc[p][o] = 0.f;
    __syncthreads();
    const float4* ws = (const float4*)(Wih1 + (size_t)pl * EMB + half * 16);
    const float4* as = (const float4*)(emb + (size_t)stok[pl] * EMB + half * 16);
    float4 qw[2][4], qe[2][4];
#pragma unroll
    for (int kc = 0; kc < 2; ++kc)
#pragma unroll
        for (int k = 0; k < 4; ++k) {
            qw[kc][k] = ws[kc * 8 + k];
            qe[kc][k] = as[kc * 8 + k];
        }
    for (int kc = 0; kc < 2; ++kc) {
        {
            const int jb = half * 16;
#pragma unroll
            for (int k = 0; k < 4; ++k) {
                float4 q = qw[kc][k], e = qe[kc][k];
                sW[jb + 4*k + 0][pl] = q.x; sW[jb + 4*k + 1][pl] = q.y;
                sW[jb + 4*k + 2][pl] = q.z; sW[jb + 4*k + 3][pl] = q.w;
                sA[jb + 4*k + 0][pl] = e.x; sA[jb + 4*k + 1][pl] = e.y;
                sA[jb + 4*k + 2][pl] = e.z; sA[jb + 4*k + 3][pl] = e.w;
            }
        }
        __syncthreads();
#pragma unroll 4
        for (int j = 0; j < 32; ++j) {
            float4 a0 = *(const float4*)&sA[j][py];
            float4 a1 = *(const float4*)&sA[j][py + 4];
            float4 b0 = *(const float4*)&sW[j][ox];
            float4 b1 = *(const float4*)&sW[j][ox + 4];
            float av[8] = {a0.x,a0.y,a0.z,a0.w,a1.x,a1.y,a1.z,a1.w};
            float bv[8] = {b0.x,b0.y,b0.z,b0.w,b1.x,b1.y,b1.z,b1.w};
#pragma unroll
            for (int p = 0; p < 8; ++p)
#pragma unroll
                for (int o = 0; o < 8; ++o)
                    acc[p][o] = fmaf(av[p], bv[o], acc[p][o]);
        }
        __syncthreads();
    }
    float bo[8];
#pragma unroll
    for (int o = 0; o < 8; ++o) bo[o] = bih1[ox + o] + bhh1[ox + o];
#pragma unroll
    for (int p = 0; p < 8; ++p) {
        float* cp = pre1 + (size_t)(base + py + p) * HID + ox;
        *(float4*)cp       = make_float4(acc[p][0]+bo[0], acc[p][1]+bo[1], acc[p][2]+bo[2], acc[p][3]+bo[3]);
        *(float4*)(cp + 4) = make_float4(acc[p][4]+bo[4], acc[p][5]+bo[5], acc[p][6]+bo[6], acc[p][7]+bo[7]);
    }
}

// block-wide sum for 768 threads (12 waves); pass 0 from non-contributing lanes
__device__ inline float bsum768(float v, volatile float* sc, int tid) {
#pragma unroll
    for (int off = 32; off > 0; off >>= 1) v += __shfl_down(v, off, 64);
    __syncthreads();
    if ((tid & 63) == 0) sc[tid >> 6] = v;
    __syncthreads();
    float s = 0.f;
#pragma unroll
    for (int k = 0; k < 12; ++k) s += sc[k];
    return s;
}

// ---------------- kernel 2: FUSED two-layer recurrence + LN/proj/LN epilogue.
// R16/R18 EXACT (374.5 µs measured, twice reproduced): 4-way K-split x
// 2 rows/thread; one h-read feeds two dots. q wave-uniform -> broadcast
// reads conflict-free. 64 pinned floats/thread (proven-safe budget).
__global__ __launch_bounds__(768)
__attribute__((amdgpu_waves_per_eu(1, 3)))
void k_rnn_fused(
    const float* __restrict__ pre1, const float* __restrict__ Whh1,
    const float* __restrict__ Wih2, const float* __restrict__ bih2,
    const float* __restrict__ bhh2, const float* __restrict__ Whh2,
    const float* __restrict__ ln_g, const float* __restrict__ ln_b,
    const float* __restrict__ projW, const float* __restrict__ proj_b,
    const float* __restrict__ on_g, const float* __restrict__ on_b,
    float* __restrict__ out)
{
    __shared__ __align__(16) float    h1b[2][HID];   // fp32 h1 (recurrent, A)
    __shared__ __align__(16) _Float16 h1h[2][HID];   // fp16 h1 copy (B, FF path)
    __shared__ __align__(16) float    h2b[2][HID];   // fp32 h2 (recurrent, C)
    __shared__ __align__(16) float sp[3][4][HID];    // 4-way K-split partials
    __shared__ __align__(16) float spre[CH * HID];   // staged pre1 rows (16 KB)
    __shared__ float sfin[HID];
    __shared__ float sc[12];
    const int b   = blockIdx.x;
    const int tid = threadIdx.x;
    const int g   = tid >> 8;         // 0=A,1=B,2=C
    const int gt  = tid & 255;
    const int q   = gt >> 6;          // K-quarter (wave-uniform)
    const int r0  = gt & 63;          // owns rows r0 and r0+64
    const int i   = gt & 127;         // publisher index
    const float* wbase = (g == 0) ? Whh1 : ((g == 1) ? Wih2 : Whh2);
    const float4* wr0 = reinterpret_cast<const float4*>(wbase + (size_t)r0 * HID + q * 32);
    const float4* wr1 = reinterpret_cast<const float4*>(wbase + (size_t)(r0 + 64) * HID + q * 32);
    WDUALLOAD; W16PIN;
    const float bias2 = (g == 1) ? (bih2[i] + bhh2[i]) : 0.f;
    if (tid < 128) {
        h1b[0][tid] = 0.f; h1h[0][tid] = (_Float16)0.f; h2b[0][tid] = 0.f;
    }
    const float4* gsrc = reinterpret_cast<const float4*>(pre1 + (size_t)b * 512 * HID);
    float4*       spv  = reinterpret_cast<float4*>(spre);
    __syncthreads();
    for (int c = 0; c < 512 / CH; ++c) {
        // stage CH pre1 rows: 1024 float4, threads 0..511 take 2 each
        if (tid < 512) {
            float4 rr0 = gsrc[c * 1024 + tid];
            float4 rr1 = gsrc[c * 1024 + tid + 512];
            spv[tid]       = rr0;
            spv[tid + 512] = rr1;
        }
        __syncthreads();
        for (int s = 0; s < CH; ++s) {
            const int t = c * CH + s;
            float a0 = 0, a1 = 0, a2 = 0, a3 = 0;
            float c0 = 0, c1 = 0, c2 = 0, c3 = 0;
            if (g == 1) {               // fp16 h1 read (feed-forward path)
                const uint4* hsrc = reinterpret_cast<const uint4*>(h1h[t & 1] + q * 32);
                DOT32H2(hsrc);
            } else {                    // fp32 recurrent reads
                const float* hsel = (g == 0) ? h1b[t & 1] : h2b[t & 1];
                const float4* hp = reinterpret_cast<const float4*>(hsel + q * 32);
                DACC8;
            }
            sp[g][q][r0]      = (a0 + a1) + (a2 + a3);
            sp[g][q][r0 + 64] = (c0 + c1) + (c2 + c3);
            __syncthreads();
            if (tid < 128) {               // waves 0-1: publish h1_t (both formats)
                float hn = fast_tanh(spre[s * HID + i] +
                    ((sp[0][0][i] + sp[0][1][i]) + (sp[0][2][i] + sp[0][3][i])));
                h1b[(t + 1) & 1][i] = hn;
                h1h[(t + 1) & 1][i] = (_Float16)hn;
            } else if (g == 1 && gt < 128) {  // waves 4-5: publish h2_{t-1}
                float v = bias2 +
                    ((sp[1][0][i] + sp[1][1][i]) + (sp[1][2][i] + sp[1][3][i])) +
                    ((sp[2][0][i] + sp[2][1][i]) + (sp[2][2][i] + sp[2][3][i]));
                h2b[(t + 1) & 1][i] = (t > 0) ? fast_tanh(v) : 0.f;
            }
            __syncthreads();
        }
    }
    // drain: h2_511 = tanh(bias2 + Wih2@h1_511 + Whh2@h2_510)
    {
        float a0 = 0, a1 = 0, a2 = 0, a3 = 0;
        float c0 = 0, c1 = 0, c2 = 0, c3 = 0;
        if (g == 1) {
            const uint4* hsrc = reinterpret_cast<const uint4*>(h1h[0] + q * 32);
            DOT32H2(hsrc);
            sp[1][q][r0]      = (a0 + a1) + (a2 + a3);
            sp[1][q][r0 + 64] = (c0 + c1) + (c2 + c3);
        } else if (g == 2) {
            const float4* hp = reinterpret_cast<const float4*>(h2b[0] + q * 32);
            DACC8;
            sp[2][q][r0]      = (a0 + a1) + (a2 + a3);
            sp[2][q][r0 + 64] = (c0 + c1) + (c2 + c3);
        }
    }
    __syncthreads();
    if (g == 1 && gt < 128)
        sfin[i] = fast_tanh(bias2 +
            ((sp[1][0][i] + sp[1][1][i]) + (sp[1][2][i] + sp[1][3][i])) +
            ((sp[2][0][i] + sp[2][1][i]) + (sp[2][2][i] + sp[2][3][i])));
    __syncthreads();
    // ---- epilogue: LN -> proj+tanh -> LN (values on tid<128; all barrier)
    float hn = (tid < 128) ? sfin[i] : 0.f;
    float s1 = bsum768(hn, sc, tid);
    float s2 = bsum768(hn * hn, sc, tid);
    float mu = s1 * (1.f / 128.f);
    float var = s2 * (1.f / 128.f) - mu * mu;
    __syncthreads();
    if (tid < 128) spre[i] = (hn - mu) * rsqrtf(var + 1e-5f) * ln_g[i] + ln_b[i];
    __syncthreads();
    float pv = 0.f;
    if (tid < 128) {
        float a0 = proj_b[i], a1 = 0, a2 = 0, a3 = 0;
        const float4* hp = reinterpret_cast<const float4*>(spre);
        const float4* pr = reinterpret_cast<const float4*>(projW + (size_t)i * HID);
#pragma unroll
        for (int k = 0; k < HID / 4; ++k) {
            float4 u = pr[k];
            float4 hv = hp[k];
            a0 = fmaf(hv.x, u.x, a0); a1 = fmaf(hv.y, u.y, a1);
            a2 = fmaf(hv.z, u.z, a2); a3 = fmaf(hv.w, u.w, a3);
        }
        pv = tanhf((a0 + a1) + (a2 + a3));
    }
    float t1 = bsum768(pv, sc, tid);
    float t2 = bsum768(pv * pv, sc, tid);
    float mu2 = t1 * (1.f / 128.f);
    float var2 = t2 * (1.f / 128.f) - mu2 * mu2;
    if (tid < 128)
        out[(size_t)b * HID + i] = (pv - mu2) * rsqrtf(var2 + 1e-5f) * on_g[i] + on_b[i];
}

extern "C" void kernel_launch(void* const* d_in, const int* in_sizes, int n_in,
                              void* d_out, int out_size, void* d_ws, size_t ws_size,
                              hipStream_t stream)
{
    const int*   x     = (const int*)  d_in[0];
    const float* emb   = (const float*)d_in[1];
    const float* Wih1  = (const float*)d_in[2];
    const float* bih1  = (const float*)d_in[3];
    const float* Whh1  = (const float*)d_in[4];
    const float* bhh1  = (const float*)d_in[5];
    const float* Wih2  = (const float*)d_in[6];
    const float* bih2  = (const float*)d_in[7];
    const float* Whh2  = (const float*)d_in[8];
    const float* bhh2  = (const float*)d_in[9];
    const float* ln_g  = (const float*)d_in[10];
    const float* ln_b  = (const float*)d_in[11];
    const float* projW = (const float*)d_in[12];
    const float* projb = (const float*)d_in[13];
    const float* on_g  = (const float*)d_in[14];
    const float* on_b  = (const float*)d_in[15];

    float* pre1 = (float*)d_ws;   // 64 MiB fp32

    k_embed_pre1<<<BT / 128, 256, 0, stream>>>(x, emb, Wih1, bih1, bhh1, pre1);
    k_rnn_fused<<<256, 768, 0, stream>>>(pre1, Whh1, Wih2, bih2, bhh2, Whh2,
                                         ln_g, ln_b, projW, projb, on_g, on_b,
                                         (float*)d_out);
}

// Round 21
// 468.673 us; speedup vs baseline: 1.0118x; 1.0118x over previous
//
#include <hip/hip_runtime.h>

#define BT (256*512)   // 131072 positions
#define HID 128
#define EMB 64
#define CH 32          // scan chunk: steps staged per LDS refill

typedef _Float16 half2_t __attribute__((ext_vector_type(2)));

__device__ inline float fast_tanh(float x) {   // 1 - 2/(exp(2x)+1), ~1e-6 abs err
    float e = __expf(2.f * x);
    return 1.f - __fdividef(2.f, e + 1.f);
}

// pin a float4 in VGPRs (compiler cannot rematerialize past this) — R6 recipe
#define OPQ(v) asm volatile("" : "+v"(v.x), "+v"(v.y), "+v"(v.z), "+v"(v.w))
#define W16PIN \
    OPQ(w0);OPQ(w1);OPQ(w2);OPQ(w3);OPQ(w4);OPQ(w5);OPQ(w6);OPQ(w7); \
    OPQ(w8);OPQ(w9);OPQ(w10);OPQ(w11);OPQ(w12);OPQ(w13);OPQ(w14);OPQ(w15);
// dual-row load: w0..w7 = row r0 K-slice, w8..w15 = row r0+64 same K-slice
#define WDUALLOAD \
    float4 w0=wr0[0],w1=wr0[1],w2=wr0[2],w3=wr0[3],w4=wr0[4],w5=wr0[5],w6=wr0[6],w7=wr0[7], \
           w8=wr1[0],w9=wr1[1],w10=wr1[2],w11=wr1[3],w12=wr1[4],w13=wr1[5],w14=wr1[6],w15=wr1[7];

// fp32 dual-row dot over a 32-value h slice: 8 b128 reads shared by 2 rows
#define DACC(n, m) { float4 hv = hp[n]; \
    a0=fmaf(hv.x,w##n.x,a0); a1=fmaf(hv.y,w##n.y,a1); \
    a2=fmaf(hv.z,w##n.z,a2); a3=fmaf(hv.w,w##n.w,a3); \
    c0=fmaf(hv.x,w##m.x,c0); c1=fmaf(hv.y,w##m.y,c1); \
    c2=fmaf(hv.z,w##m.z,c2); c3=fmaf(hv.w,w##m.w,c3); }
#define DACC8 DACC(0,8) DACC(1,9) DACC(2,10) DACC(3,11) \
              DACC(4,12) DACC(5,13) DACC(6,14) DACC(7,15)

// fp16 dual-row dot over a 32-value h slice: 4 uint4 reads shared by 2 rows
#define BCH(u) __builtin_bit_cast(half2_t, u)
#define FMX2(qq, wa, wb, wc, wd) { \
    half2_t p0=BCH(qq.x), p1=BCH(qq.y), p2=BCH(qq.z), p3=BCH(qq.w); \
    float f0=(float)p0.x, f1=(float)p0.y, f2=(float)p1.x, f3=(float)p1.y, \
          f4=(float)p2.x, f5=(float)p2.y, f6=(float)p3.x, f7=(float)p3.y; \
    a0=fmaf(f0,wa.x,a0); a1=fmaf(f1,wa.y,a1); a2=fmaf(f2,wa.z,a2); a3=fmaf(f3,wa.w,a3); \
    a0=fmaf(f4,wb.x,a0); a1=fmaf(f5,wb.y,a1); a2=fmaf(f6,wb.z,a2); a3=fmaf(f7,wb.w,a3); \
    c0=fmaf(f0,wc.x,c0); c1=fmaf(f1,wc.y,c1); c2=fmaf(f2,wc.z,c2); c3=fmaf(f3,wc.w,c3); \
    c0=fmaf(f4,wd.x,c0); c1=fmaf(f5,wd.y,c1); c2=fmaf(f6,wd.z,c2); c3=fmaf(f7,wd.w,c3); }
#define DOT32H2(hsrc) \
    { uint4 q0h=hsrc[0],q1h=hsrc[1],q2h=hsrc[2],q3h=hsrc[3]; \
      FMX2(q0h,w0,w1,w8,w9) FMX2(q1h,w2,w3,w10,w11) \
      FMX2(q2h,w4,w5,w12,w13) FMX2(q3h,w6,w7,w14,w15) }

// ---------------- kernel 1: embedding gather + layer-1 input GEMM (R15 form)
__global__ __launch_bounds__(256)
__attribute__((amdgpu_waves_per_eu(1, 2)))
void k_embed_pre1(
    const int* __restrict__ x, const float* __restrict__ emb,
    const float* __restrict__ Wih1, const float* __restrict__ bih1,
    const float* __restrict__ bhh1, float* __restrict__ pre1)
{
    __shared__ float sA[32][128];
    __shared__ float sW[32][132];
    __shared__ int stok[128];
    const int tid = threadIdx.x;
    const int base = blockIdx.x * 128;
    const int tx = tid & 15, ty = tid >> 4;
    const int ox = tx * 8, py = ty * 8;
    const int pl = tid & 127, half = tid >> 7;
    if (tid < 128) stok[tid] = x[base + tid];
    float acc[8][8];
#pragma unroll
    for (int p = 0; p < 8; ++p)
#pragma unroll
        for (int o = 0; o < 8; ++o) acc[p][o] = 0.f;
    __syncthreads();
    const float4* ws = (const float4*)(Wih1 + (size_t)pl * EMB + half * 16);
    const float4* as = (const float4*)(emb + (size_t)stok[pl] * EMB + half * 16);
    float4 qw[2][4], qe[2][4];
#pragma unroll
    for (int kc = 0; kc < 2; ++kc)
#pragma unroll
        for (int k = 0; k < 4; ++k) {
            qw[kc][k] = ws[kc * 8 + k];
            qe[kc][k] = as[kc * 8 + k];
        }
    for (int kc = 0; kc < 2; ++kc) {
        {
            const int jb = half * 16;
#pragma unroll
            for (int k = 0; k < 4; ++k) {
                float4 q = qw[kc][k], e = qe[kc][k];
                sW[jb + 4*k + 0][pl] = q.x; sW[jb + 4*k + 1][pl] = q.y;
                sW[jb + 4*k + 2][pl] = q.z; sW[jb + 4*k + 3][pl] = q.w;
                sA[jb + 4*k + 0][pl] = e.x; sA[jb + 4*k + 1][pl] = e.y;
                sA[jb + 4*k + 2][pl] = e.z; sA[jb + 4*k + 3][pl] = e.w;
            }
        }
        __syncthreads();
#pragma unroll 4
        for (int j = 0; j < 32; ++j) {
            float4 a0 = *(const float4*)&sA[j][py];
            float4 a1 = *(const float4*)&sA[j][py + 4];
            float4 b0 = *(const float4*)&sW[j][ox];
            float4 b1 = *(const float4*)&sW[j][ox + 4];
            float av[8] = {a0.x,a0.y,a0.z,a0.w,a1.x,a1.y,a1.z,a1.w};
            float bv[8] = {b0.x,b0.y,b0.z,b0.w,b1.x,b1.y,b1.z,b1.w};
#pragma unroll
            for (int p = 0; p < 8; ++p)
#pragma unroll
                for (int o = 0; o < 8; ++o)
                    acc[p][o] = fmaf(av[p], bv[o], acc[p][o]);
        }
        __syncthreads();
    }
    float bo[8];
#pragma unroll
    for (int o = 0; o < 8; ++o) bo[o] = bih1[ox + o] + bhh1[ox + o];
#pragma unroll
    for (int p = 0; p < 8; ++p) {
        float* cp = pre1 + (size_t)(base + py + p) * HID + ox;
        *(float4*)cp       = make_float4(acc[p][0]+bo[0], acc[p][1]+bo[1], acc[p][2]+bo[2], acc[p][3]+bo[3]);
        *(float4*)(cp + 4) = make_float4(acc[p][4]+bo[4], acc[p][5]+bo[5], acc[p][6]+bo[6], acc[p][7]+bo[7]);
    }
}

// block-wide sum for 768 threads (12 waves); pass 0 from non-contributing lanes
__device__ inline float bsum768(float v, volatile float* sc, int tid) {
#pragma unroll
    for (int off = 32; off > 0; off >>= 1) v += __shfl_down(v, off, 64);
    __syncthreads();
    if ((tid & 63) == 0) sc[tid >> 6] = v;
    __syncthreads();
    float s = 0.f;
#pragma unroll
    for (int k = 0; k < 12; ++k) s += sc[k];
    return s;
}

// ---------------- kernel 2: FUSED two-layer recurrence + LN/proj/LN epilogue.
// R16/R18 EXACT (374.5 µs measured, twice reproduced): 4-way K-split x
// 2 rows/thread; one h-read feeds two dots. q wave-uniform -> broadcast
// reads conflict-free. 64 pinned floats/thread (proven-safe budget).
__global__ __launch_bounds__(768)
__attribute__((amdgpu_waves_per_eu(1, 3)))
void k_rnn_fused(
    const float* __restrict__ pre1, const float* __restrict__ Whh1,
    const float* __restrict__ Wih2, const float* __restrict__ bih2,
    const float* __restrict__ bhh2, const float* __restrict__ Whh2,
    const float* __restrict__ ln_g, const float* __restrict__ ln_b,
    const float* __restrict__ projW, const float* __restrict__ proj_b,
    const float* __restrict__ on_g, const float* __restrict__ on_b,
    float* __restrict__ out)
{
    __shared__ __align__(16) float    h1b[2][HID];   // fp32 h1 (recurrent, A)
    __shared__ __align__(16) _Float16 h1h[2][HID];   // fp16 h1 copy (B, FF path)
    __shared__ __align__(16) float    h2b[2][HID];   // fp32 h2 (recurrent, C)
    __shared__ __align__(16) float sp[3][4][HID];    // 4-way K-split partials
    __shared__ __align__(16) float spre[CH * HID];   // staged pre1 rows (16 KB)
    __shared__ float sfin[HID];
    __shared__ float sc[12];
    const int b   = blockIdx.x;
    const int tid = threadIdx.x;
    const int g   = tid >> 8;         // 0=A,1=B,2=C
    const int gt  = tid & 255;
    const int q   = gt >> 6;          // K-quarter (wave-uniform)
    const int r0  = gt & 63;          // owns rows r0 and r0+64
    const int i   = gt & 127;         // publisher index
    const float* wbase = (g == 0) ? Whh1 : ((g == 1) ? Wih2 : Whh2);
    const float4* wr0 = reinterpret_cast<const float4*>(wbase + (size_t)r0 * HID + q * 32);
    const float4* wr1 = reinterpret_cast<const float4*>(wbase + (size_t)(r0 + 64) * HID + q * 32);
    WDUALLOAD; W16PIN;
    const float bias2 = (g == 1) ? (bih2[i] + bhh2[i]) : 0.f;
    if (tid < 128) {
        h1b[0][tid] = 0.f; h1h[0][tid] = (_Float16)0.f; h2b[0][tid] = 0.f;
    }
    const float4* gsrc = reinterpret_cast<const float4*>(pre1 + (size_t)b * 512 * HID);
    float4*       spv  = reinterpret_cast<float4*>(spre);
    __syncthreads();
    for (int c = 0; c < 512 / CH; ++c) {
        // stage CH pre1 rows: 1024 float4, threads 0..511 take 2 each
        if (tid < 512) {
            float4 rr0 = gsrc[c * 1024 + tid];
            float4 rr1 = gsrc[c * 1024 + tid + 512];
            spv[tid]       = rr0;
            spv[tid + 512] = rr1;
        }
        __syncthreads();
        for (int s = 0; s < CH; ++s) {
            const int t = c * CH + s;
            float a0 = 0, a1 = 0, a2 = 0, a3 = 0;
            float c0 = 0, c1 = 0, c2 = 0, c3 = 0;
            if (g == 1) {               // fp16 h1 read (feed-forward path)
                const uint4* hsrc = reinterpret_cast<const uint4*>(h1h[t & 1] + q * 32);
                DOT32H2(hsrc);
            } else {                    // fp32 recurrent reads
                const float* hsel = (g == 0) ? h1b[t & 1] : h2b[t & 1];
                const float4* hp = reinterpret_cast<const float4*>(hsel + q * 32);
                DACC8;
            }
            sp[g][q][r0]      = (a0 + a1) + (a2 + a3);
            sp[g][q][r0 + 64] = (c0 + c1) + (c2 + c3);
            __syncthreads();
            if (tid < 128) {               // waves 0-1: publish h1_t (both formats)
                float hn = fast_tanh(spre[s * HID + i] +
                    ((sp[0][0][i] + sp[0][1][i]) + (sp[0][2][i] + sp[0][3][i])));
                h1b[(t + 1) & 1][i] = hn;
                h1h[(t + 1) & 1][i] = (_Float16)hn;
            } else if (g == 1 && gt < 128) {  // waves 4-5: publish h2_{t-1}
                float v = bias2 +
                    ((sp[1][0][i] + sp[1][1][i]) + (sp[1][2][i] + sp[1][3][i])) +
                    ((sp[2][0][i] + sp[2][1][i]) + (sp[2][2][i] + sp[2][3][i]));
                h2b[(t + 1) & 1][i] = (t > 0) ? fast_tanh(v) : 0.f;
            }
            __syncthreads();
        }
    }
    // drain: h2_511 = tanh(bias2 + Wih2@h1_511 + Whh2@h2_510)
    {
        float a0 = 0, a1 = 0, a2 = 0, a3 = 0;
        float c0 = 0, c1 = 0, c2 = 0, c3 = 0;
        if (g == 1) {
            const uint4* hsrc = reinterpret_cast<const uint4*>(h1h[0] + q * 32);
            DOT32H2(hsrc);
            sp[1][q][r0]      = (a0 + a1) + (a2 + a3);
            sp[1][q][r0 + 64] = (c0 + c1) + (c2 + c3);
        } else if (g == 2) {
            const float4* hp = reinterpret_cast<const float4*>(h2b[0] + q * 32);
            DACC8;
            sp[2][q][r0]      = (a0 + a1) + (a2 + a3);
            sp[2][q][r0 + 64] = (c0 + c1) + (c2 + c3);
        }
    }
    __syncthreads();
    if (g == 1 && gt < 128)
        sfin[i] = fast_tanh(bias2 +
            ((sp[1][0][i] + sp[1][1][i]) + (sp[1][2][i] + sp[1][3][i])) +
            ((sp[2][0][i] + sp[2][1][i]) + (sp[2][2][i] + sp[2][3][i])));
    __syncthreads();
    // ---- epilogue: LN -> proj+tanh -> LN (values on tid<128; all barrier)
    float hn = (tid < 128) ? sfin[i] : 0.f;
    float s1 = bsum768(hn, sc, tid);
    float s2 = bsum768(hn * hn, sc, tid);
    float mu = s1 * (1.f / 128.f);
    float var = s2 * (1.f / 128.f) - mu * mu;
    __syncthreads();
    if (tid < 128) spre[i] = (hn - mu) * rsqrtf(var + 1e-5f) * ln_g[i] + ln_b[i];
    __syncthreads();
    float pv = 0.f;
    if (tid < 128) {
        float a0 = proj_b[i], a1 = 0, a2 = 0, a3 = 0;
        const float4* hp = reinterpret_cast<const float4*>(spre);
        const float4* pr = reinterpret_cast<const float4*>(projW + (size_t)i * HID);
#pragma unroll
        for (int k = 0; k < HID / 4; ++k) {
            float4 u = pr[k];
            float4 hv = hp[k];
            a0 = fmaf(hv.x, u.x, a0); a1 = fmaf(hv.y, u.y, a1);
            a2 = fmaf(hv.z, u.z, a2); a3 = fmaf(hv.w, u.w, a3);
        }
        pv = tanhf((a0 + a1) + (a2 + a3));
    }
    float t1 = bsum768(pv, sc, tid);
    float t2 = bsum768(pv * pv, sc, tid);
    float mu2 = t1 * (1.f / 128.f);
    float var2 = t2 * (1.f / 128.f) - mu2 * mu2;
    if (tid < 128)
        out[(size_t)b * HID + i] = (pv - mu2) * rsqrtf(var2 + 1e-5f) * on_g[i] + on_b[i];
}

extern "C" void kernel_launch(void* const* d_in, const int* in_sizes, int n_in,
                              void* d_out, int out_size, void* d_ws, size_t ws_size,
                              hipStream_t stream)
{
    const int*   x     = (const int*)  d_in[0];
    const float* emb   = (const float*)d_in[1];
    const float* Wih1  = (const float*)d_in[2];
    const float* bih1  = (const float*)d_in[3];
    const float* Whh1  = (const float*)d_in[4];
    const float* bhh1  = (const float*)d_in[5];
    const float* Wih2  = (const float*)d_in[6];
    const float* bih2  = (const float*)d_in[7];
    const float* Whh2  = (const float*)d_in[8];
    const float* bhh2  = (const float*)d_in[9];
    const float* ln_g  = (const float*)d_in[10];
    const float* ln_b  = (const float*)d_in[11];
    const float* projW = (const float*)d_in[12];
    const float* projb = (const float*)d_in[13];
    const float* on_g  = (const float*)d_in[14];
    const float* on_b  = (const float*)d_in[15];

    float* pre1 = (float*)d_ws;   // 64 MiB fp32

    k_embed_pre1<<<BT / 128, 256, 0, stream>>>(x, emb, Wih1, bih1, bhh1, pre1);
    k_rnn_fused<<<256, 768, 0, stream>>>(pre1, Whh1, Wih2, bih2, bhh2, Whh2,
                                         ln_g, ln_b, projW, projb, on_g, on_b,
                                         (float*)d_out);
}